// Round 10
// baseline (82.047 us; speedup 1.0000x reference)
//
#include <hip/hip_runtime.h>
#include <stdint.h>

typedef float    f32x4  __attribute__((ext_vector_type(4)));
typedef __bf16   bf16x8 __attribute__((ext_vector_type(8)));
typedef uint32_t u32x4  __attribute__((ext_vector_type(4)));
typedef unsigned short u16x4 __attribute__((ext_vector_type(4)));

#define AS1 __attribute__((address_space(1)))
#define AS3 __attribute__((address_space(3)))

__device__ __forceinline__ unsigned short f2bf_bits(float f) {
  uint32_t u = __builtin_bit_cast(uint32_t, f);
  u += 0x7fffu + ((u >> 16) & 1u);      // RNE to bf16
  return (unsigned short)(u >> 16);
}

// ---------------- kernel 0: At[col][k] (bf16) = A[k][col] ----------------
__global__ void k_transpose_cvt(const float* __restrict__ A,
                                unsigned short* __restrict__ At) {
  int n = blockIdx.x * blockDim.x + threadIdx.x;  // 65536 threads
  int o = n << 2;
  int col = o >> 8;
  int k   = o & 255;
  u16x4 v;
#pragma unroll
  for (int j = 0; j < 4; ++j) v[j] = f2bf_bits(A[(size_t)(k + j) * 1024 + col]);
  *reinterpret_cast<u16x4*>(At + o) = v;
}

// ---------------- kernel 1: fused GEMM + silu rowsum + fill + diag -------
// 512 blocks x 256 threads, 2 blocks/CU (8 waves/CU = 2/SIMD).
// Block = 2 groups. Wave w: group gpair*2+(w>>1), half h=w&1 (32 x-rows,
// 2 row-groups -> 16 MFMA per 8 ds_read). Block-SHARED staging: 4 x 8KB LDS
// buffers, each tile staged once per block (wave stages chunks 2w,2w+1).
// Per iter: [2 global_load_lds (tile t+2) | 2 f32x4 zero-stores (2 rows)]
// then fused s_waitcnt vmcnt(10)+s_barrier. Stores never drained in-loop.
// Epilogue: vmcnt(0)+barrier, shfl-reduce, write diag entries.
__launch_bounds__(256, 2)
__global__ void k_fused(const float* __restrict__ x,
                        const unsigned short* __restrict__ At,
                        float* __restrict__ out) {
  __shared__ alignas(16) char lds[4][8192];

  const int tid  = threadIdx.x;
  const int lane = tid & 63;
  const int w    = tid >> 6;             // wave 0..3
  const int h    = w & 1;                // half-group
  const int g    = blockIdx.x * 2 + (w >> 1);   // group 0..1023

  const int col = lane & 15;             // A row / B col / C col
  const int hi  = lane >> 4;             // k-subblock select

  // staging: wave stages chunks 2w, 2w+1 of each 8KB tile. LDS linear chunk
  // p (16B) <- global (p ^ swz(p)); swz flips bits 4..6 keyed by bits 9..11
  // (col) -> conflict-free b128 reads with the same XOR on the read side.
  uint32_t p0  = (uint32_t)((w * 2 + 0) * 1024 + lane * 16);
  uint32_t so0 = p0 ^ (((p0 >> 9) & 7u) << 4);
  uint32_t p1  = (uint32_t)((w * 2 + 1) * 1024 + lane * 16);
  uint32_t so1 = p1 ^ (((p1 >> 9) & 7u) << 4);
  const uint32_t d0 = (uint32_t)(w * 2 + 0) * 1024;
  const uint32_t d1 = (uint32_t)(w * 2 + 1) * 1024;

  // ---- prologue: stage tiles 0,1 into bufs 0,1 ----
#pragma unroll
  for (int t = 0; t < 2; ++t) {
    const char* src = (const char*)At + (size_t)t * 8192;
    __builtin_amdgcn_global_load_lds((const AS1 uint32_t*)(src + so0),
                                     (AS3 uint32_t*)(lds[t] + d0), 16, 0, 0);
    __builtin_amdgcn_global_load_lds((const AS1 uint32_t*)(src + so1),
                                     (AS3 uint32_t*)(lds[t] + d1), 16, 0, 0);
  }
  __builtin_amdgcn_sched_barrier(0);   // keep x loads below the prefetches

  // ---- x fragments: rg r -> x-row g*64 + h*32 + r*16 + col ----
  bf16x8 xf[2][8];
#pragma unroll
  for (int r = 0; r < 2; ++r) {
    const float* xr = x + (size_t)(g * 64 + h * 32 + r * 16 + col) * 256;
#pragma unroll
    for (int s = 0; s < 8; ++s) {
      f32x4 a = __builtin_nontemporal_load(
          reinterpret_cast<const f32x4*>(xr + s * 32 + hi * 8));
      f32x4 bq = __builtin_nontemporal_load(
          reinterpret_cast<const f32x4*>(xr + s * 32 + hi * 8 + 4));
      bf16x8 f;
      f[0] = (__bf16)a[0];  f[1] = (__bf16)a[1];
      f[2] = (__bf16)a[2];  f[3] = (__bf16)a[3];
      f[4] = (__bf16)bq[0]; f[5] = (__bf16)bq[1];
      f[6] = (__bf16)bq[2]; f[7] = (__bf16)bq[3];
      xf[r][s] = f;
    }
  }
  // drain prologue (x loads + tile 0,1 stages), join all waves
  asm volatile("s_waitcnt vmcnt(0)\n\ts_barrier" ::: "memory");

  // B-frag read: byte col*512 + s*64 + hi*16, XOR (col&7)<<4; disjoint bit
  // fields -> addr(s) = rbase ^ (s<<6)
  uint32_t rbase = ((uint32_t)(col * 512 + hi * 16)) ^ ((uint32_t)(col & 7) << 4);

  float sums[2][4] = {{0.f,0.f,0.f,0.f},{0.f,0.f,0.f,0.f}};
  float* og = out + (size_t)g * 65536;     // group's 256KB slab
  float* fillbase = og + (size_t)h * 32768 + lane * 4;  // wave's half-slab
  const f32x4 z4 = {0.f, 0.f, 0.f, 0.f};

  for (int t = 0; t < 64; ++t) {
    // stage tile (t+2)&63 into buf (t+2)&3 (uniform 4-op/iter vmem pattern)
    {
      int pt = (t + 2) & 63;
      const char* src = (const char*)At + (size_t)pt * 8192;
      char* dst = lds[(t + 2) & 3];
      __builtin_amdgcn_global_load_lds((const AS1 uint32_t*)(src + so0),
                                       (AS3 uint32_t*)(dst + d0), 16, 0, 0);
      __builtin_amdgcn_global_load_lds((const AS1 uint32_t*)(src + so1),
                                       (AS3 uint32_t*)(dst + d1), 16, 0, 0);
    }
    __builtin_amdgcn_sched_barrier(0);   // pin [L,L] before the stores
    // zero-fill 2 contiguous out-rows (2KB) of the wave's half-slab
    {
      float* zp = fillbase + t * 512;    // rows h*128 + 2t, +1
      __builtin_nontemporal_store(z4, reinterpret_cast<f32x4*>(zp));
      __builtin_nontemporal_store(z4, reinterpret_cast<f32x4*>(zp + 256));
    }
    // wait for tile t's 2 loads (issued 2 iters ago; younger ops:
    // 2S(t-2) + 4(t-1) + 4(t) = 10), then cross-wave barrier. Fused so
    // nothing schedules between wait and barrier.
    asm volatile("s_waitcnt vmcnt(10)\n\ts_barrier" ::: "memory");

    const char* buf = lds[t & 3];
    bf16x8 bfr[8];
#pragma unroll
    for (int s = 0; s < 8; ++s) {
      uint32_t addr = rbase ^ ((uint32_t)s << 6);
      bfr[s] = __builtin_bit_cast(
          bf16x8, *reinterpret_cast<const u32x4*>(buf + addr));
    }
    // 4 independent MFMA chains: 2 rgs x 2 K-halves
    f32x4 a00 = {0.f,0.f,0.f,0.f}, a01 = {0.f,0.f,0.f,0.f};
    f32x4 a10 = {0.f,0.f,0.f,0.f}, a11 = {0.f,0.f,0.f,0.f};
#pragma unroll
    for (int s = 0; s < 4; ++s) {
      a00 = __builtin_amdgcn_mfma_f32_16x16x32_bf16(xf[0][s],     bfr[s],     a00, 0, 0, 0);
      a01 = __builtin_amdgcn_mfma_f32_16x16x32_bf16(xf[0][s + 4], bfr[s + 4], a01, 0, 0, 0);
      a10 = __builtin_amdgcn_mfma_f32_16x16x32_bf16(xf[1][s],     bfr[s],     a10, 0, 0, 0);
      a11 = __builtin_amdgcn_mfma_f32_16x16x32_bf16(xf[1][s + 4], bfr[s + 4], a11, 0, 0, 0);
    }
#pragma unroll
    for (int j = 0; j < 4; ++j) {
      float z0 = a00[j] + a01[j];
      float z1 = a10[j] + a11[j];
      float s0 = __builtin_amdgcn_rcpf(1.0f + __expf(-z0));
      float s1 = __builtin_amdgcn_rcpf(1.0f + __expf(-z1));
      sums[0][j] += z0 * s0;
      sums[1][j] += z1 * s1;
    }
    // WAR safe: buf (t+2)&3's last reads (tile t-2) completed before
    // barrier(t-1), and this write is issued after barrier(t-1).
  }

  // drain all zero-stores, join waves (diag rows span both halves' fills)
  asm volatile("s_waitcnt vmcnt(0)\n\ts_barrier" ::: "memory");

  // reduce over the 16 column-lanes (C layout: col = lane&15)
#pragma unroll
  for (int r = 0; r < 2; ++r)
#pragma unroll
    for (int j = 0; j < 4; ++j) {
      float v = sums[r][j];
      v += __shfl_xor(v, 1, 64);
      v += __shfl_xor(v, 2, 64);
      v += __shfl_xor(v, 4, 64);
      v += __shfl_xor(v, 8, 64);
      sums[r][j] = v;
    }

  if (col == 0) {
#pragma unroll
    for (int r = 0; r < 2; ++r)
#pragma unroll
      for (int j = 0; j < 4; ++j) {
        int c = h * 32 + r * 16 + hi * 4 + j;   // x-row within group, 0..63
        float s = sums[r][j];
        og[(2 * c) * 256 + 128 + 2 * c]     =  s;   // out[g, i, 128+i], i=2c
        og[(2 * c + 1) * 256 + 129 + 2 * c] =  s;   // i=2c+1
        og[(128 + 2 * c) * 256 + 2 * c]     = -s;   // out[g, 128+i, i]
        og[(129 + 2 * c) * 256 + 2 * c + 1] = -s;
      }
  }
}

extern "C" void kernel_launch(void* const* d_in, const int* in_sizes, int n_in,
                              void* d_out, int out_size, void* d_ws, size_t ws_size,
                              hipStream_t stream) {
  const float* x = (const float*)d_in[0];   // [65536, 256]
  const float* A = (const float*)d_in[1];   // [256, 1024]
  float* out = (float*)d_out;               // [1024, 256, 256]
  unsigned short* At = (unsigned short*)d_ws;  // 512 KB bf16 transposed weights

  k_transpose_cvt<<<256, 256, 0, stream>>>(A, At);
  k_fused<<<512, 256, 0, stream>>>(x, At, out);
}